// Round 6
// baseline (489.013 us; speedup 1.0000x reference)
//
#include <hip/hip_runtime.h>

// Problem constants: B=512, L=128, N=64, H=16, PW=30, FEAT=480
#define LSX 65    // xs row stride (64+1)
#define FCS 40    // fcmm LDS row stride (32+8 ushorts)

typedef __bf16 bf16x8 __attribute__((ext_vector_type(8)));
typedef float  f32x4  __attribute__((ext_vector_type(4)));

__device__ __forceinline__ unsigned short f2bf_rne(float x) {
    unsigned int u = __float_as_uint(x);
    unsigned int r = u + 0x7FFFu + ((u >> 16) & 1u);
    return (unsigned short)(r >> 16);
}

// ---------------------------------------------------------------------------
// Kernel 0: Wih0 [64,480] -> MFMA B-fragment layout, bf16 hi/lo
// ---------------------------------------------------------------------------
__global__ __launch_bounds__(256) void k_permW(const float* __restrict__ Wih0,
                                               unsigned short* __restrict__ Wfh,
                                               unsigned short* __restrict__ Wfl)
{
    int idx = blockIdx.x * 256 + threadIdx.x;     // < 30720
    int j = idx & 7, lane = (idx >> 3) & 63, nt = (idx >> 9) & 3, ch = idx >> 11;
    int g = nt * 16 + (lane & 15);
    int k = (lane >> 4) * 8 + j;
    int f = ch * 32 + k, q = f >> 4, h = f & 15;
    float v = Wih0[g * 480 + h * 30 + q];
    unsigned int uv = __float_as_uint(v);
    Wfh[idx] = (unsigned short)(uv >> 16);
    Wfl[idx] = f2bf_rne(v - __uint_as_float(uv & 0xFFFF0000u));
}

// ---------------------------------------------------------------------------
// Kernel 0b: generic fp32 -> bf16 hi/lo split (per float4)
// ---------------------------------------------------------------------------
__global__ __launch_bounds__(256) void k_cvt(const float* __restrict__ in,
                                             unsigned short* __restrict__ oh,
                                             unsigned short* __restrict__ ol,
                                             int n4)
{
    int i = blockIdx.x * 256 + threadIdx.x;
    if (i >= n4) return;
    float4 v = ((const float4*)in)[i];
    float vv[4] = {v.x, v.y, v.z, v.w};
    unsigned short hs[4], ls[4];
    #pragma unroll
    for (int e = 0; e < 4; ++e) {
        unsigned int u = __float_as_uint(vv[e]);
        hs[e] = (unsigned short)(u >> 16);
        ls[e] = f2bf_rne(vv[e] - __uint_as_float(u & 0xFFFF0000u));
    }
    uint2 ph = make_uint2((unsigned)hs[0] | ((unsigned)hs[1] << 16),
                          (unsigned)hs[2] | ((unsigned)hs[3] << 16));
    uint2 pl = make_uint2((unsigned)ls[0] | ((unsigned)ls[1] << 16),
                          (unsigned)ls[2] | ((unsigned)ls[3] << 16));
    *(uint2*)&oh[i * 4] = ph;
    *(uint2*)&ol[i * 4] = pl;
}

// ---------------------------------------------------------------------------
// Kernel 1: dual-axis attention + conv/bn/pool + MFMA GEMM.  [unchanged]
// ---------------------------------------------------------------------------
__global__ __launch_bounds__(256, 3) void k_attn_conv(
    const float* __restrict__ x1, const float* __restrict__ x2,
    const float* __restrict__ w_x_q, const float* __restrict__ w_x_k,
    const float* __restrict__ w_y_q, const float* __restrict__ w_y_k,
    const float* __restrict__ pos_emb,
    const float* __restrict__ conv_w, const float* __restrict__ conv_b,
    const float* __restrict__ bn_g, const float* __restrict__ bn_b,
    const float* __restrict__ bn_m, const float* __restrict__ bn_v,
    const unsigned short* __restrict__ Wfh, const unsigned short* __restrict__ Wfl,
    float* __restrict__ pre0)
{
    __shared__ float xs[128 * LSX];
    __shared__ float xk[64], ykv[128], uu[64], vv[128], sxs[128], sys[64];
    __shared__ float cw[16][4], cbs[16], bnsc[16], bnsh[16];

    const int bg = blockIdx.x;
    const int t  = threadIdx.x;
    const float* x = (bg < 512 ? x1 : x2) + (size_t)(bg & 511) * 8192;

    #pragma unroll
    for (int r = 0; r < 32; ++r) {
        int pos = r * 256 + t;
        xs[(pos >> 6) * LSX + (pos & 63)] = x[pos];
    }
    if (t < 16) {
        float sc = bn_g[t] * rsqrtf(bn_v[t] + 1e-5f);
        bnsc[t] = sc;
        bnsh[t] = bn_b[t] - bn_m[t] * sc;
        cbs[t]  = conv_b[t];
        cw[t][0] = conv_w[t * 4 + 0]; cw[t][1] = conv_w[t * 4 + 1];
        cw[t][2] = conv_w[t * 4 + 2]; cw[t][3] = conv_w[t * 4 + 3];
    }
    __syncthreads();

    if (t < 64) {
        float s = 0.f;
        for (int l = 0; l < 128; ++l) s += xs[l * LSX + t] * w_x_k[l];
        xk[t] = s;
    } else if (t < 192) {
        int l = t - 64;
        float s = 0.f;
        for (int n = 0; n < 64; ++n) s += w_y_k[n] * xs[l * LSX + n];
        ykv[l] = s;
    }
    __syncthreads();

    if (t < 64) {
        float s = 0.f;
        for (int n = 0; n < 64; ++n) s += w_x_q[t * 64 + n] * xk[n];
        uu[t] = s;
    } else if (t < 192) {
        int m = t - 64;
        float s = 0.f;
        for (int l = 0; l < 128; ++l) s += ykv[l] * w_y_q[l * 128 + m];
        vv[m] = s;
    }
    __syncthreads();

    if (t < 128) {
        float s = 0.f;
        for (int m = 0; m < 64; ++m) s += xs[t * LSX + m] * uu[m];
        sxs[t] = s;
    } else if (t < 192) {
        int n = t - 128;
        float s = 0.f;
        for (int m = 0; m < 128; ++m) s += vv[m] * xs[m * LSX + n];
        sys[n] = s;
    }
    __syncthreads();

    if (t < 64) {
        float a = sxs[t], b = sxs[t + 64];
        float mx = fmaxf(a, b);
        #pragma unroll
        for (int d = 32; d > 0; d >>= 1) mx = fmaxf(mx, __shfl_xor(mx, d, 64));
        float e0 = __expf(a - mx), e1 = __expf(b - mx);
        float s = e0 + e1;
        #pragma unroll
        for (int d = 32; d > 0; d >>= 1) s += __shfl_xor(s, d, 64);
        float r = 10.f / s;
        sxs[t] = e0 * r; sxs[t + 64] = e1 * r;
    } else if (t < 128) {
        int n = t - 64;
        float a = sys[n];
        float mx = a;
        #pragma unroll
        for (int d = 32; d > 0; d >>= 1) mx = fmaxf(mx, __shfl_xor(mx, d, 64));
        float e = __expf(a - mx);
        float s = e;
        #pragma unroll
        for (int d = 32; d > 0; d >>= 1) s += __shfl_xor(s, d, 64);
        sys[n] = e * (10.f / s);
    }
    __syncthreads();

    #pragma unroll
    for (int r = 0; r < 32; ++r) {
        int pos = r * 256 + t;
        int l = pos >> 6, n = pos & 63;
        xs[l * LSX + n] = xs[l * LSX + n] * sxs[l] * sys[n] + pos_emb[pos];
    }
    __syncthreads();

    const int lane = t & 63, w = t >> 6;
    const int m16 = lane & 15, kq = lane >> 4;
    const int hb = (kq & 1) * 8;
    const int qoff = kq >> 1;

    float cwr0[8], cwr1[8], cwr2[8], cwr3[8], cbr[8], bsr[8], bhr[8];
    #pragma unroll
    for (int j = 0; j < 8; ++j) {
        cwr0[j] = cw[hb + j][0]; cwr1[j] = cw[hb + j][1];
        cwr2[j] = cw[hb + j][2]; cwr3[j] = cw[hb + j][3];
        cbr[j] = cbs[hb + j]; bsr[j] = bnsc[hb + j]; bhr[j] = bnsh[hb + j];
    }

    f32x4 acc[2][4];
    #pragma unroll
    for (int mt = 0; mt < 2; ++mt)
        #pragma unroll
        for (int nt = 0; nt < 4; ++nt) {
            f32x4 z = {0.f, 0.f, 0.f, 0.f};
            acc[mt][nt] = z;
        }

    for (int ch = 0; ch < 15; ++ch) {
        bf16x8 bh[4], bl[4];
        #pragma unroll
        for (int nt = 0; nt < 4; ++nt) {
            int o = ((ch * 4 + nt) * 64 + lane) * 8;
            bh[nt] = *(const bf16x8*)&Wfh[o];
            bl[nt] = *(const bf16x8*)&Wfl[o];
        }
        bf16x8 ah[2], al[2];
        const int q2 = 2 * (2 * ch + qoff);
        #pragma unroll
        for (int mt = 0; mt < 2; ++mt) {
            int row = w * 32 + mt * 16 + m16;
            const float* xr = &xs[row * LSX + q2];
            float o0 = xr[0], o1 = xr[1], o2 = xr[2], o3 = xr[3], o4 = xr[4];
            union { unsigned short us[8]; bf16x8 bv; } vh, vl;
            #pragma unroll
            for (int j = 0; j < 8; ++j) {
                float a = fmaf(o0, cwr0[j], fmaf(o1, cwr1[j], fmaf(o2, cwr2[j], fmaf(o3, cwr3[j], cbr[j]))));
                float b = fmaf(o1, cwr0[j], fmaf(o2, cwr1[j], fmaf(o3, cwr2[j], fmaf(o4, cwr3[j], cbr[j]))));
                a = fmaf(fmaxf(a, 0.f), bsr[j], bhr[j]);
                b = fmaf(fmaxf(b, 0.f), bsr[j], bhr[j]);
                float v = fmaxf(a, b);
                unsigned int uv = __float_as_uint(v);
                vh.us[j] = (unsigned short)(uv >> 16);
                vl.us[j] = f2bf_rne(v - __uint_as_float(uv & 0xFFFF0000u));
            }
            ah[mt] = vh.bv; al[mt] = vl.bv;
        }
        #pragma unroll
        for (int mt = 0; mt < 2; ++mt)
            #pragma unroll
            for (int nt = 0; nt < 4; ++nt) {
                acc[mt][nt] = __builtin_amdgcn_mfma_f32_16x16x32_bf16(ah[mt], bh[nt], acc[mt][nt], 0, 0, 0);
                acc[mt][nt] = __builtin_amdgcn_mfma_f32_16x16x32_bf16(al[mt], bh[nt], acc[mt][nt], 0, 0, 0);
                acc[mt][nt] = __builtin_amdgcn_mfma_f32_16x16x32_bf16(ah[mt], bl[nt], acc[mt][nt], 0, 0, 0);
            }
    }

    #pragma unroll
    for (int mt = 0; mt < 2; ++mt)
        #pragma unroll
        for (int nt = 0; nt < 4; ++nt)
            #pragma unroll
            for (int r = 0; r < 4; ++r) {
                int row = w * 32 + mt * 16 + (lane >> 4) * 4 + r;
                int col = nt * 16 + m16;
                pre0[(size_t)bg * 8192 + row * 64 + col] = acc[mt][nt][r];
            }
}

// ---------------------------------------------------------------------------
// Kernel 2: fused 2-layer LSTM, xor-gather edition.
// lane = torch gate-row = g*16+u (g=lane>>4: 0=i,1=f,2=g,3=o; u=lane&15).
// Each lane keeps h of its own unit; matvec partners come from ds_swizzle
// xor ops with weights pre-gathered per-lane in xor order. Gate exchange:
// 1 swizzle + 2 shfl_xor(32) + 8 cndmask per layer. No readlane, no barrier.
// Pipelined: each iteration computes {L1(t) || L0(t+1)}.
// ---------------------------------------------------------------------------
#define SWZ(X, S) __uint_as_float((unsigned)__builtin_amdgcn_ds_swizzle( \
        (int)__float_as_uint(X), ((S) << 10) | 0x1F))

#define SEL4(P, V, X16, X32, X48)                 \
    float P##0 = gb0 ? (X16) : (V);               \
    float P##1 = gb0 ? (V) : (X16);               \
    float P##2 = gb0 ? (X48) : (X32);             \
    float P##3 = gb0 ? (X32) : (X48);             \
    float P##si = gb1 ? P##2 : P##0;              \
    float P##sf = gb1 ? P##3 : P##1;              \
    float P##tg = gb1 ? P##0 : P##2;              \
    float P##so = gb1 ? P##1 : P##3;

#define ROT(S, A) {                               \
    float r0_ = SWZ(hr0, S);                      \
    float r1_ = SWZ(hr1, S);                      \
    x##A = fmaf(r0_, w0r[S], x##A);               \
    i##A = fmaf(r0_, wi1r[S], i##A);              \
    h##A = fmaf(r1_, wh1r[S], h##A);              \
}

__global__ __launch_bounds__(64) void k_lstm(
    const float* __restrict__ pre0,
    const float* __restrict__ Whh0,
    const float* __restrict__ Wih1, const float* __restrict__ Whh1,
    const float* __restrict__ bih0, const float* __restrict__ bhh0,
    const float* __restrict__ bih1, const float* __restrict__ bhh1,
    unsigned short* __restrict__ fbh, unsigned short* __restrict__ fbl)
{
    const int blk = blockIdx.x;
    const int i = blk >> 7, j = blk & 127;
    const int lane = threadIdx.x;
    const int g = lane >> 4, u = lane & 15;
    const bool gb0 = (g & 1) != 0, gb1 = (g & 2) != 0;
    const bool st = (g == 0);

    float w0r[16], wi1r[16], wh1r[16];
    #pragma unroll
    for (int s = 0; s < 16; ++s) {
        int m = u ^ s;
        w0r[s]  = Whh0[lane * 16 + m];
        wi1r[s] = Wih1[lane * 16 + m];
        wh1r[s] = Whh1[lane * 16 + m];
    }
    const float b0 = bih0[lane] + bhh0[lane];
    const float b1 = bih1[lane] + bhh1[lane];
    const float pm = (g == 2) ? -2.f : -1.f;
    const float ka = (g == 2) ?  2.f :  1.f;
    const float kb = (g == 2) ? -1.f :  0.f;

    const float* pp = pre0 + (size_t)i * 4194304 + (size_t)j * 64 + lane;
    const size_t fbase = (size_t)i * 1048576 + (size_t)j * 16 + u;

    float hr0, hr1 = 0.f, c0, c1 = 0.f;

    // prologue: L0(0) with h0 = 0
    {
        float g0v = pp[0] + b0;
        float v = fmaf(__builtin_amdgcn_rcpf(1.f + __expf(pm * g0v)), ka, kb);
        float z16 = SWZ(v, 16);
        float z32 = __shfl_xor(v, 32, 64);
        float z48 = __shfl_xor(z16, 32, 64);
        SEL4(p, v, z16, z32, z48)
        c0 = psi * ptg;
        hr0 = pso * fmaf(-2.f, __builtin_amdgcn_rcpf(__expf(2.f * c0) + 1.f), 1.f);
    }

    float pf[8];
    #pragma unroll
    for (int d = 0; d < 8; ++d) pf[d] = pp[(size_t)(1 + d) * 8192];

#define STEP2(PF, TT) {                                                         \
        float xA = hr0 * w0r[0], xB = 0.f, xC = 0.f, xD = 0.f;                  \
        float iA = hr0 * wi1r[0], iB = 0.f, iC = 0.f, iD = 0.f;                 \
        float hA = hr1 * wh1r[0], hB = 0.f, hC = 0.f, hD = 0.f;                 \
        ROT(1, B) ROT(2, C) ROT(3, D) ROT(4, A)                                 \
        ROT(5, B) ROT(6, C) ROT(7, D) ROT(8, A)                                 \
        ROT(9, B) ROT(10, C) ROT(11, D) ROT(12, A)                              \
        ROT(13, B) ROT(14, C) ROT(15, D)                                        \
        float g1v = b1 + ((iA + iB) + (iC + iD)) + ((hA + hB) + (hC + hD));     \
        float g0v = (PF) + b0 + ((xA + xB) + (xC + xD));                        \
        float v1 = fmaf(__builtin_amdgcn_rcpf(1.f + __expf(pm * g1v)), ka, kb); \
        float v0 = fmaf(__builtin_amdgcn_rcpf(1.f + __expf(pm * g0v)), ka, kb); \
        float y16 = SWZ(v1, 16);                                                \
        float z16 = SWZ(v0, 16);                                                \
        float y32 = __shfl_xor(v1, 32, 64);                                     \
        float z32 = __shfl_xor(v0, 32, 64);                                     \
        float y48 = __shfl_xor(y16, 32, 64);                                    \
        float z48 = __shfl_xor(z16, 32, 64);                                    \
        SEL4(q, v1, y16, y32, y48)                                              \
        SEL4(r, v0, z16, z32, z48)                                              \
        c1 = fmaf(qsf, c1, qsi * qtg);                                          \
        c0 = fmaf(rsf, c0, rsi * rtg);                                          \
        float h1n = qso * fmaf(-2.f, __builtin_amdgcn_rcpf(__expf(2.f * c1) + 1.f), 1.f); \
        float h0n = rso * fmaf(-2.f, __builtin_amdgcn_rcpf(__expf(2.f * c0) + 1.f), 1.f); \
        if (st) {                                                               \
            unsigned int uh = __float_as_uint(h1n);                             \
            fbh[fbase + (size_t)(TT) * 2048] = (unsigned short)(uh >> 16);      \
            fbl[fbase + (size_t)(TT) * 2048] =                                  \
                f2bf_rne(h1n - __uint_as_float(uh & 0xFFFF0000u));              \
        }                                                                       \
        hr1 = h1n;                                                              \
        hr0 = h0n;                                                              \
    }

    for (int tb = 0; tb < 64; ++tb) {
        const int base = tb * 8;
        float nx[8];
        #pragma unroll
        for (int d = 0; d < 8; ++d) nx[d] = pp[(size_t)(base + 9 + d) * 8192];
        STEP2(pf[0], base + 0);
        STEP2(pf[1], base + 1);
        STEP2(pf[2], base + 2);
        STEP2(pf[3], base + 3);
        STEP2(pf[4], base + 4);
        STEP2(pf[5], base + 5);
        STEP2(pf[6], base + 6);
        STEP2(pf[7], base + 7);
        #pragma unroll
        for (int d = 0; d < 8; ++d) pf[d] = nx[d];
    }
#undef STEP2
}

// ---------------------------------------------------------------------------
// Kernel 3/4: MFMA bf16 GEMM on pre-split hi/lo inputs.  [unchanged]
// ---------------------------------------------------------------------------
__global__ __launch_bounds__(256) void k_fcmm(
    const unsigned short* __restrict__ Ahg, const unsigned short* __restrict__ Alg,
    const unsigned short* __restrict__ Bhg, const unsigned short* __restrict__ Blg,
    const float* __restrict__ bias,
    float* __restrict__ Cf, unsigned short* __restrict__ Chh,
    unsigned short* __restrict__ Chl,
    int N, int K)
{
    __shared__ unsigned short Ah[128 * FCS], Al[128 * FCS];
    __shared__ unsigned short Bh[128 * FCS], Bl[128 * FCS];
    const int t = threadIdx.x;
    const int lane = t & 63, w = t >> 6;
    const int wr = (w >> 1) * 64, wc = (w & 1) * 64;
    const int m0 = blockIdx.y * 128, n0 = blockIdx.x * 128;
    const int m16 = lane & 15, kb = (lane >> 4) * 8;

    f32x4 acc[4][4];
    #pragma unroll
    for (int mt = 0; mt < 4; ++mt)
        #pragma unroll
        for (int nt = 0; nt < 4; ++nt) {
            f32x4 z = {0.f, 0.f, 0.f, 0.f};
            acc[mt][nt] = z;
        }

    for (int kc = 0; kc < K; kc += 32) {
        #pragma unroll
        for (int si = 0; si < 2; ++si) {
            int s = t * 2 + si;
            int r = s >> 2, kg = (s & 3) * 8;
            size_t ga = (size_t)(m0 + r) * K + kc + kg;
            size_t gb = (size_t)(n0 + r) * K + kc + kg;
            *(uint4*)&Ah[r * FCS + kg] = *(const uint4*)&Ahg[ga];
            *(uint4*)&Al[r * FCS + kg] = *(const uint4*)&Alg[ga];
            *(uint4*)&Bh[r * FCS + kg] = *(const uint4*)&Bhg[gb];
            *(uint4*)&Bl[r * FCS + kg] = *(const uint4*)&Blg[gb];
        }
        __syncthreads();

        bf16x8 afh[4], afl[4], bfh[4], bfl[4];
        #pragma unroll
        for (int mt = 0; mt < 4; ++mt) {
            int off = (wr + mt * 16 + m16) * FCS + kb;
            afh[mt] = *(const bf16x8*)&Ah[off];
            afl[mt] = *(const bf16x8*)&Al[off];
        }
        #pragma unroll
        for (int nt = 0; nt < 4; ++nt) {
            int off = (wc + nt * 16 + m16) * FCS + kb;
            bfh[nt] = *(const bf16x8*)&Bh[off];
            bfl[nt] = *(const bf16x8*)&Bl[off];
        }
        #pragma unroll
        for (int mt = 0; mt < 4; ++mt)
            #pragma unroll
            for (int nt = 0; nt < 4; ++nt) {
                acc[mt][nt] = __builtin_amdgcn_mfma_f32_16x16x32_bf16(afh[mt], bfh[nt], acc[mt][nt], 0, 0, 0);
                acc[mt][nt] = __builtin_amdgcn_mfma_f32_16x16x32_bf16(afl[mt], bfh[nt], acc[mt][nt], 0, 0, 0);
                acc[mt][nt] = __builtin_amdgcn_mfma_f32_16x16x32_bf16(afh[mt], bfl[nt], acc[mt][nt], 0, 0, 0);
            }
        __syncthreads();
    }

    #pragma unroll
    for (int mt = 0; mt < 4; ++mt)
        #pragma unroll
        for (int nt = 0; nt < 4; ++nt)
            #pragma unroll
            for (int r = 0; r < 4; ++r) {
                int rr = m0 + wr + mt * 16 + (lane >> 4) * 4 + r;
                int cc = n0 + wc + nt * 16 + m16;
                float v = acc[mt][nt][r] + bias[cc];
                v = (v > 0.f) ? v : 0.01f * v;
                if (Cf) {
                    Cf[(size_t)rr * N + cc] = v;
                } else {
                    unsigned int uv = __float_as_uint(v);
                    Chh[(size_t)rr * N + cc] = (unsigned short)(uv >> 16);
                    Chl[(size_t)rr * N + cc] =
                        f2bf_rne(v - __uint_as_float(uv & 0xFFFF0000u));
                }
            }
}

// ---------------------------------------------------------------------------
// Kernel 5: FC3 [1024,1024] @ [20,1024]^T + bias -> d_out [1024,20]
// ---------------------------------------------------------------------------
__global__ __launch_bounds__(256) void k_fc3(
    const float* __restrict__ A, const float* __restrict__ W,
    const float* __restrict__ bias, float* __restrict__ out)
{
    __shared__ float row[1024];
    __shared__ float red[20][8];
    const int m = blockIdx.x;
    const int t = threadIdx.x;
    #pragma unroll
    for (int r = 0; r < 4; ++r) row[r * 256 + t] = A[(size_t)m * 1024 + r * 256 + t];
    __syncthreads();
    if (t < 160) {
        int o = t >> 3, seg = t & 7;
        const float* w = W + (size_t)o * 1024 + seg * 128;
        const float* rr = &row[seg * 128];
        float s = 0.f;
        for (int kk = 0; kk < 128; ++kk) s += rr[kk] * w[kk];
        red[o][seg] = s;
    }
    __syncthreads();
    if (t < 20) {
        float s = bias[t];
        #pragma unroll
        for (int seg = 0; seg < 8; ++seg) s += red[t][seg];
        out[(size_t)m * 20 + t] = s;
    }
}

// ---------------------------------------------------------------------------
extern "C" void kernel_launch(void* const* d_in, const int* in_sizes, int n_in,
                              void* d_out, int out_size, void* d_ws, size_t ws_size,
                              hipStream_t stream) {
    const float* in1    = (const float*)d_in[0];
    const float* in2    = (const float*)d_in[1];
    const float* w_x_q  = (const float*)d_in[2];
    const float* w_x_k  = (const float*)d_in[3];
    const float* w_y_q  = (const float*)d_in[4];
    const float* w_y_k  = (const float*)d_in[5];
    const float* posemb = (const float*)d_in[6];
    const float* conv_w = (const float*)d_in[7];
    const float* conv_b = (const float*)d_in[8];
    const float* bn_g   = (const float*)d_in[9];
    const float* bn_b   = (const float*)d_in[10];
    const float* bn_m   = (const float*)d_in[11];
    const float* bn_v   = (const float*)d_in[12];
    const float* Wih0   = (const float*)d_in[13];
    const float* Whh0   = (const float*)d_in[14];
    const float* bih0   = (const float*)d_in[15];
    const float* bhh0   = (const float*)d_in[16];
    const float* Wih1   = (const float*)d_in[17];
    const float* Whh1   = (const float*)d_in[18];
    const float* bih1   = (const float*)d_in[19];
    const float* bhh1   = (const float*)d_in[20];
    const float* fc1w   = (const float*)d_in[21];
    const float* fc1b   = (const float*)d_in[22];
    const float* fc2w   = (const float*)d_in[23];
    const float* fc2b   = (const float*)d_in[24];
    const float* fc3w   = (const float*)d_in[25];
    const float* fc3b   = (const float*)d_in[26];
    float* out = (float*)d_out;

    float* ws = (float*)d_ws;
    float* pre0            = ws;                               // 8,466,432
    unsigned short* fbh    = (unsigned short*)(ws + 8466432);  // 2,097,152 us
    unsigned short* fbl    = (unsigned short*)(ws + 9515008);
    unsigned short* f1h    = (unsigned short*)(ws + 10563584); // 1,048,576 us
    unsigned short* f1l    = (unsigned short*)(ws + 11087872);
    float* f2              = ws + 11612160;                    // 1,048,576 f
    unsigned short* w1h    = (unsigned short*)(ws + 12660736); // 2,097,152 us
    unsigned short* w1l    = (unsigned short*)(ws + 13709312);
    unsigned short* w2h    = (unsigned short*)(ws + 14757888); // 1,048,576 us
    unsigned short* w2l    = (unsigned short*)(ws + 15282176);
    unsigned short* Wfh    = (unsigned short*)(ws + 15806464); // 30,720 us
    unsigned short* Wfl    = (unsigned short*)(ws + 15821824);

    k_permW<<<120, 256, 0, stream>>>(Wih0, Wfh, Wfl);
    k_cvt<<<2048, 256, 0, stream>>>(fc1w, w1h, w1l, 524288);
    k_cvt<<<1024, 256, 0, stream>>>(fc2w, w2h, w2l, 262144);
    k_attn_conv<<<1024, 256, 0, stream>>>(in1, in2, w_x_q, w_x_k, w_y_q, w_y_k,
                                          posemb, conv_w, conv_b, bn_g, bn_b,
                                          bn_m, bn_v, Wfh, Wfl, pre0);
    k_lstm<<<256, 64, 0, stream>>>(pre0, Whh0, Wih1, Whh1,
                                   bih0, bhh0, bih1, bhh1, fbh, fbl);
    dim3 gfc(8, 8);
    k_fcmm<<<gfc, 256, 0, stream>>>(fbh, fbl, w1h, w1l, fc1b,
                                    nullptr, f1h, f1l, 1024, 2048);
    k_fcmm<<<gfc, 256, 0, stream>>>(f1h, f1l, w2h, w2l, fc2b,
                                    f2, nullptr, nullptr, 1024, 1024);
    k_fc3<<<1024, 256, 0, stream>>>(f2, fc3w, fc3b, out);
}

// Round 7
// 389.398 us; speedup vs baseline: 1.2558x; 1.2558x over previous
//
#include <hip/hip_runtime.h>

// Problem constants: B=512, L=128, N=64, H=16, PW=30, FEAT=480
#define LSX 65    // xs row stride (64+1)
#define FCS 40    // fcmm LDS row stride (32+8 ushorts)

typedef __bf16 bf16x8 __attribute__((ext_vector_type(8)));
typedef float  f32x4  __attribute__((ext_vector_type(4)));

__device__ __forceinline__ unsigned short f2bf_rne(float x) {
    unsigned int u = __float_as_uint(x);
    unsigned int r = u + 0x7FFFu + ((u >> 16) & 1u);
    return (unsigned short)(r >> 16);
}

// quad_perm broadcast of quad-lane Q (DPP ctrl = Q*0x55)
#define QB(x, C) __uint_as_float((unsigned)__builtin_amdgcn_update_dpp( \
        0, (int)__float_as_uint(x), (C), 0xF, 0xF, false))
#define RDLANE(x, L) __uint_as_float((unsigned)__builtin_amdgcn_readlane( \
        (int)__float_as_uint(x), (L)))

// ---------------------------------------------------------------------------
// Kernel 0: Wih0 [64,480] -> MFMA B-fragment layout, bf16 hi/lo
// ---------------------------------------------------------------------------
__global__ __launch_bounds__(256) void k_permW(const float* __restrict__ Wih0,
                                               unsigned short* __restrict__ Wfh,
                                               unsigned short* __restrict__ Wfl)
{
    int idx = blockIdx.x * 256 + threadIdx.x;     // < 30720
    int j = idx & 7, lane = (idx >> 3) & 63, nt = (idx >> 9) & 3, ch = idx >> 11;
    int g = nt * 16 + (lane & 15);
    int k = (lane >> 4) * 8 + j;
    int f = ch * 32 + k, q = f >> 4, h = f & 15;
    float v = Wih0[g * 480 + h * 30 + q];
    unsigned int uv = __float_as_uint(v);
    Wfh[idx] = (unsigned short)(uv >> 16);
    Wfl[idx] = f2bf_rne(v - __uint_as_float(uv & 0xFFFF0000u));
}

// ---------------------------------------------------------------------------
// Kernel 0b: generic fp32 -> bf16 hi/lo split (per float4)
// ---------------------------------------------------------------------------
__global__ __launch_bounds__(256) void k_cvt(const float* __restrict__ in,
                                             unsigned short* __restrict__ oh,
                                             unsigned short* __restrict__ ol,
                                             int n4)
{
    int i = blockIdx.x * 256 + threadIdx.x;
    if (i >= n4) return;
    float4 v = ((const float4*)in)[i];
    float vv[4] = {v.x, v.y, v.z, v.w};
    unsigned short hs[4], ls[4];
    #pragma unroll
    for (int e = 0; e < 4; ++e) {
        unsigned int u = __float_as_uint(vv[e]);
        hs[e] = (unsigned short)(u >> 16);
        ls[e] = f2bf_rne(vv[e] - __uint_as_float(u & 0xFFFF0000u));
    }
    uint2 ph = make_uint2((unsigned)hs[0] | ((unsigned)hs[1] << 16),
                          (unsigned)hs[2] | ((unsigned)hs[3] << 16));
    uint2 pl = make_uint2((unsigned)ls[0] | ((unsigned)ls[1] << 16),
                          (unsigned)ls[2] | ((unsigned)ls[3] << 16));
    *(uint2*)&oh[i * 4] = ph;
    *(uint2*)&ol[i * 4] = pl;
}

// ---------------------------------------------------------------------------
// Kernel 1: dual-axis attention + conv/bn/pool + MFMA GEMM.
// Attention phases: split-K column reductions, all 256 threads active.
// ---------------------------------------------------------------------------
__global__ __launch_bounds__(256, 3) void k_attn_conv(
    const float* __restrict__ x1, const float* __restrict__ x2,
    const float* __restrict__ w_x_q, const float* __restrict__ w_x_k,
    const float* __restrict__ w_y_q, const float* __restrict__ w_y_k,
    const float* __restrict__ pos_emb,
    const float* __restrict__ conv_w, const float* __restrict__ conv_b,
    const float* __restrict__ bn_g, const float* __restrict__ bn_b,
    const float* __restrict__ bn_m, const float* __restrict__ bn_v,
    const unsigned short* __restrict__ Wfh, const unsigned short* __restrict__ Wfl,
    float* __restrict__ pre0)
{
    __shared__ float xs[128 * LSX];
    __shared__ float xkp[2][64], ykv[128], uu[64], vv[128];
    __shared__ float sxs[128], sysp[2][64], sys[64];
    __shared__ float cw[16][4], cbs[16], bnsc[16], bnsh[16];

    const int bg = blockIdx.x;
    const int t  = threadIdx.x;
    const float* x = (bg < 512 ? x1 : x2) + (size_t)(bg & 511) * 8192;

    #pragma unroll
    for (int r = 0; r < 32; ++r) {
        int pos = r * 256 + t;
        xs[(pos >> 6) * LSX + (pos & 63)] = x[pos];
    }
    if (t < 16) {
        float sc = bn_g[t] * rsqrtf(bn_v[t] + 1e-5f);
        bnsc[t] = sc;
        bnsh[t] = bn_b[t] - bn_m[t] * sc;
        cbs[t]  = conv_b[t];
        cw[t][0] = conv_w[t * 4 + 0]; cw[t][1] = conv_w[t * 4 + 1];
        cw[t][2] = conv_w[t * 4 + 2]; cw[t][3] = conv_w[t * 4 + 3];
    }
    __syncthreads();

    // phase 1: xk partials (split-K over l) + ykv rows, all threads active
    if (t < 128) {
        int n = t & 63, hf = t >> 6;
        const float* base = &xs[hf * 64 * LSX + n];
        const float* wk = w_x_k + hf * 64;
        float s = 0.f;
        for (int l = 0; l < 64; ++l) s += base[l * LSX] * wk[l];
        xkp[hf][n] = s;
    } else {
        int l = t - 128;
        const float* row = &xs[l * LSX];
        float s = 0.f;
        for (int n = 0; n < 64; ++n) s += w_y_k[n] * row[n];
        ykv[l] = s;
    }
    __syncthreads();

    // phase 2: uu[m] (xk combined inline), vv[m]
    if (t < 64) {
        const float* wq = w_x_q + t * 64;
        float s = 0.f;
        for (int n = 0; n < 64; ++n) s += wq[n] * (xkp[0][n] + xkp[1][n]);
        uu[t] = s;
    } else if (t < 192) {
        int m = t - 64;
        float s = 0.f;
        for (int l = 0; l < 128; ++l) s += ykv[l] * w_y_q[l * 128 + m];
        vv[m] = s;
    }
    __syncthreads();

    // phase 3: sxs rows + sys partials (split-K over m)
    if (t < 128) {
        const float* row = &xs[t * LSX];
        float s = 0.f;
        for (int m = 0; m < 64; ++m) s += row[m] * uu[m];
        sxs[t] = s;
    } else {
        int n = (t - 128) & 63, hf = (t - 128) >> 6;
        const float* base = &xs[hf * 64 * LSX + n];
        const float* vp = vv + hf * 64;
        float s = 0.f;
        for (int m = 0; m < 64; ++m) s += vp[m] * base[m * LSX];
        sysp[hf][n] = s;
    }
    __syncthreads();

    // phase 4: softmaxes, x10
    if (t < 64) {
        float a = sxs[t], b = sxs[t + 64];
        float mx = fmaxf(a, b);
        #pragma unroll
        for (int d = 32; d > 0; d >>= 1) mx = fmaxf(mx, __shfl_xor(mx, d, 64));
        float e0 = __expf(a - mx), e1 = __expf(b - mx);
        float s = e0 + e1;
        #pragma unroll
        for (int d = 32; d > 0; d >>= 1) s += __shfl_xor(s, d, 64);
        float r = 10.f / s;
        sxs[t] = e0 * r; sxs[t + 64] = e1 * r;
    } else if (t < 128) {
        int n = t - 64;
        float a = sysp[0][n] + sysp[1][n];
        float mx = a;
        #pragma unroll
        for (int d = 32; d > 0; d >>= 1) mx = fmaxf(mx, __shfl_xor(mx, d, 64));
        float e = __expf(a - mx);
        float s = e;
        #pragma unroll
        for (int d = 32; d > 0; d >>= 1) s += __shfl_xor(s, d, 64);
        sys[n] = e * (10.f / s);
    }
    __syncthreads();

    // phase 5: out = x*sx*sy + pos_emb (in place)
    #pragma unroll
    for (int r = 0; r < 32; ++r) {
        int pos = r * 256 + t;
        int l = pos >> 6, n = pos & 63;
        xs[l * LSX + n] = xs[l * LSX + n] * sxs[l] * sys[n] + pos_emb[pos];
    }
    __syncthreads();

    // phase 6: 15 chunks of K=32; in-register feat + global W frags
    const int lane = t & 63, w = t >> 6;
    const int m16 = lane & 15, kq = lane >> 4;
    const int hb = (kq & 1) * 8;
    const int qoff = kq >> 1;

    float cwr0[8], cwr1[8], cwr2[8], cwr3[8], cbr[8], bsr[8], bhr[8];
    #pragma unroll
    for (int j = 0; j < 8; ++j) {
        cwr0[j] = cw[hb + j][0]; cwr1[j] = cw[hb + j][1];
        cwr2[j] = cw[hb + j][2]; cwr3[j] = cw[hb + j][3];
        cbr[j] = cbs[hb + j]; bsr[j] = bnsc[hb + j]; bhr[j] = bnsh[hb + j];
    }

    f32x4 acc[2][4];
    #pragma unroll
    for (int mt = 0; mt < 2; ++mt)
        #pragma unroll
        for (int nt = 0; nt < 4; ++nt) {
            f32x4 z = {0.f, 0.f, 0.f, 0.f};
            acc[mt][nt] = z;
        }

    for (int ch = 0; ch < 15; ++ch) {
        bf16x8 bh[4], bl[4];
        #pragma unroll
        for (int nt = 0; nt < 4; ++nt) {
            int o = ((ch * 4 + nt) * 64 + lane) * 8;
            bh[nt] = *(const bf16x8*)&Wfh[o];
            bl[nt] = *(const bf16x8*)&Wfl[o];
        }
        bf16x8 ah[2], al[2];
        const int q2 = 2 * (2 * ch + qoff);
        #pragma unroll
        for (int mt = 0; mt < 2; ++mt) {
            int row = w * 32 + mt * 16 + m16;
            const float* xr = &xs[row * LSX + q2];
            float o0 = xr[0], o1 = xr[1], o2 = xr[2], o3 = xr[3], o4 = xr[4];
            union { unsigned short us[8]; bf16x8 bv; } vh, vl;
            #pragma unroll
            for (int j = 0; j < 8; ++j) {
                float a = fmaf(o0, cwr0[j], fmaf(o1, cwr1[j], fmaf(o2, cwr2[j], fmaf(o3, cwr3[j], cbr[j]))));
                float b = fmaf(o1, cwr0[j], fmaf(o2, cwr1[j], fmaf(o3, cwr2[j], fmaf(o4, cwr3[j], cbr[j]))));
                a = fmaf(fmaxf(a, 0.f), bsr[j], bhr[j]);
                b = fmaf(fmaxf(b, 0.f), bsr[j], bhr[j]);
                float v = fmaxf(a, b);
                unsigned int uv = __float_as_uint(v);
                vh.us[j] = (unsigned short)(uv >> 16);
                vl.us[j] = f2bf_rne(v - __uint_as_float(uv & 0xFFFF0000u));
            }
            ah[mt] = vh.bv; al[mt] = vl.bv;
        }
        #pragma unroll
        for (int mt = 0; mt < 2; ++mt)
            #pragma unroll
            for (int nt = 0; nt < 4; ++nt) {
                acc[mt][nt] = __builtin_amdgcn_mfma_f32_16x16x32_bf16(ah[mt], bh[nt], acc[mt][nt], 0, 0, 0);
                acc[mt][nt] = __builtin_amdgcn_mfma_f32_16x16x32_bf16(al[mt], bh[nt], acc[mt][nt], 0, 0, 0);
                acc[mt][nt] = __builtin_amdgcn_mfma_f32_16x16x32_bf16(ah[mt], bl[nt], acc[mt][nt], 0, 0, 0);
            }
    }

    #pragma unroll
    for (int mt = 0; mt < 2; ++mt)
        #pragma unroll
        for (int nt = 0; nt < 4; ++nt)
            #pragma unroll
            for (int r = 0; r < 4; ++r) {
                int row = w * 32 + mt * 16 + (lane >> 4) * 4 + r;
                int col = nt * 16 + m16;
                pre0[(size_t)bg * 8192 + row * 64 + col] = acc[mt][nt][r];
            }
}

// ---------------------------------------------------------------------------
// Kernel 2: fused 2-layer LSTM — round-4 structure (181 µs measured):
// lane = unit*4 + gate; own-gate activation; DPP quad broadcasts (VALU pipe);
// readlane h-broadcast to SGPRs; 8-deep prefetch. Only change vs round 4:
// fbuf emitted as bf16 hi/lo for the fc1 MFMA GEMM.
// ---------------------------------------------------------------------------
__global__ __launch_bounds__(64) void k_lstm(
    const float* __restrict__ pre0,
    const float* __restrict__ Whh0,
    const float* __restrict__ Wih1, const float* __restrict__ Whh1,
    const float* __restrict__ bih0, const float* __restrict__ bhh0,
    const float* __restrict__ bih1, const float* __restrict__ bhh1,
    unsigned short* __restrict__ fbh, unsigned short* __restrict__ fbl)
{
    const int blk = blockIdx.x;
    const int i = blk >> 7, j = blk & 127;
    const int k = threadIdx.x;
    const int a = k & 3, u = k >> 2;
    const int row = a * 16 + u;          // torch gate-row index

    float w0[16], wi1[16], wh1[16];
    #pragma unroll
    for (int m = 0; m < 16; ++m) {
        w0[m]  = Whh0[row * 16 + m];
        wi1[m] = Wih1[row * 16 + m];
        wh1[m] = Whh1[row * 16 + m];
    }
    const float b0 = bih0[row] + bhh0[row];
    const float b1 = bih1[row] + bhh1[row];
    // unified activation: val = ka * (1/(1+exp(pm*g))) + kb
    const float pm = (a == 2) ? -2.f : -1.f;
    const float ka = (a == 2) ?  2.f :  1.f;
    const float kb = (a == 2) ? -1.f :  0.f;

    float h0[16], h1[16];
    #pragma unroll
    for (int m = 0; m < 16; ++m) { h0[m] = 0.f; h1[m] = 0.f; }
    float c0 = 0.f, c1 = 0.f;

    const float* pp = pre0 + (size_t)i * 4194304 + (size_t)j * 64 + row;
    const size_t fbase = (size_t)i * 1048576 + (size_t)j * 16 + u;
    const bool st = (a == 0);

    float pf[8];
    #pragma unroll
    for (int d = 0; d < 8; ++d) pf[d] = pp[(size_t)d * 8192];

#define LSTM_STEP(PRE, TT)                                                      \
    {                                                                           \
        float sA = 0.f, sB = 0.f, sC = 0.f, sD = 0.f;                           \
        _Pragma("unroll")                                                       \
        for (int m = 0; m < 4; ++m) {                                           \
            sA += h0[m]      * w0[m];                                           \
            sB += h0[m + 4]  * w0[m + 4];                                       \
            sC += h0[m + 8]  * w0[m + 8];                                       \
            sD += h0[m + 12] * w0[m + 12];                                      \
        }                                                                       \
        float g0 = PRE + b0 + ((sA + sB) + (sC + sD));                          \
        float e0 = __expf(pm * g0);                                             \
        float v0 = fmaf(__builtin_amdgcn_rcpf(1.f + e0), ka, kb);               \
        float si = QB(v0, 0x00), sf = QB(v0, 0x55);                             \
        float tg = QB(v0, 0xAA), so = QB(v0, 0xFF);                             \
        c0 = fmaf(sf, c0, si * tg);                                             \
        float ec = __expf(-2.f * c0);                                           \
        float h0n = so * fmaf(2.f, __builtin_amdgcn_rcpf(1.f + ec), -1.f);      \
        float hn[16];                                                           \
        _Pragma("unroll")                                                       \
        for (int m = 0; m < 16; ++m) hn[m] = RDLANE(h0n, 4 * m);                \
        float tA = 0.f, tB = 0.f, tC = 0.f, tD = 0.f;                           \
        _Pragma("unroll")                                                       \
        for (int m = 0; m < 4; ++m) {                                           \
            tA += hn[m]      * wi1[m]      + h1[m]      * wh1[m];               \
            tB += hn[m + 4]  * wi1[m + 4]  + h1[m + 4]  * wh1[m + 4];           \
            tC += hn[m + 8]  * wi1[m + 8]  + h1[m + 8]  * wh1[m + 8];           \
            tD += hn[m + 12] * wi1[m + 12] + h1[m + 12] * wh1[m + 12];          \
        }                                                                       \
        float g1 = b1 + ((tA + tB) + (tC + tD));                                \
        float e1 = __expf(pm * g1);                                             \
        float v1 = fmaf(__builtin_amdgcn_rcpf(1.f + e1), ka, kb);               \
        float si1 = QB(v1, 0x00), sf1 = QB(v1, 0x55);                           \
        float tg1 = QB(v1, 0xAA), so1 = QB(v1, 0xFF);                           \
        c1 = fmaf(sf1, c1, si1 * tg1);                                          \
        float ec1 = __expf(-2.f * c1);                                          \
        float h1n = so1 * fmaf(2.f, __builtin_amdgcn_rcpf(1.f + ec1), -1.f);    \
        if (st) {                                                               \
            unsigned int uh = __float_as_uint(h1n);                             \
            fbh[fbase + (size_t)(TT) * 2048] = (unsigned short)(uh >> 16);      \
            fbl[fbase + (size_t)(TT) * 2048] =                                  \
                f2bf_rne(h1n - __uint_as_float(uh & 0xFFFF0000u));              \
        }                                                                       \
        _Pragma("unroll")                                                       \
        for (int m = 0; m < 16; ++m) {                                          \
            h1[m] = RDLANE(h1n, 4 * m);                                         \
            h0[m] = hn[m];                                                      \
        }                                                                       \
    }

    for (int t = 0; t < 512; t += 8) {
        float nx[8];
        #pragma unroll
        for (int d = 0; d < 8; ++d) nx[d] = pp[(size_t)(t + 8 + d) * 8192];
        LSTM_STEP(pf[0], t + 0);
        LSTM_STEP(pf[1], t + 1);
        LSTM_STEP(pf[2], t + 2);
        LSTM_STEP(pf[3], t + 3);
        LSTM_STEP(pf[4], t + 4);
        LSTM_STEP(pf[5], t + 5);
        LSTM_STEP(pf[6], t + 6);
        LSTM_STEP(pf[7], t + 7);
        #pragma unroll
        for (int d = 0; d < 8; ++d) pf[d] = nx[d];
    }
#undef LSTM_STEP
}

// ---------------------------------------------------------------------------
// Kernel 3/4: MFMA bf16 GEMM on pre-split hi/lo inputs.  [unchanged]
// ---------------------------------------------------------------------------
__global__ __launch_bounds__(256) void k_fcmm(
    const unsigned short* __restrict__ Ahg, const unsigned short* __restrict__ Alg,
    const unsigned short* __restrict__ Bhg, const unsigned short* __restrict__ Blg,
    const float* __restrict__ bias,
    float* __restrict__ Cf, unsigned short* __restrict__ Chh,
    unsigned short* __restrict__ Chl,
    int N, int K)
{
    __shared__ unsigned short Ah[128 * FCS], Al[128 * FCS];
    __shared__ unsigned short Bh[128 * FCS], Bl[128 * FCS];
    const int t = threadIdx.x;
    const int lane = t & 63, w = t >> 6;
    const int wr = (w >> 1) * 64, wc = (w & 1) * 64;
    const int m0 = blockIdx.y * 128, n0 = blockIdx.x * 128;
    const int m16 = lane & 15, kb = (lane >> 4) * 8;

    f32x4 acc[4][4];
    #pragma unroll
    for (int mt = 0; mt < 4; ++mt)
        #pragma unroll
        for (int nt = 0; nt < 4; ++nt) {
            f32x4 z = {0.f, 0.f, 0.f, 0.f};
            acc[mt][nt] = z;
        }

    for (int kc = 0; kc < K; kc += 32) {
        #pragma unroll
        for (int si = 0; si < 2; ++si) {
            int s = t * 2 + si;
            int r = s >> 2, kg = (s & 3) * 8;
            size_t ga = (size_t)(m0 + r) * K + kc + kg;
            size_t gb = (size_t)(n0 + r) * K + kc + kg;
            *(uint4*)&Ah[r * FCS + kg] = *(const uint4*)&Ahg[ga];
            *(uint4*)&Al[r * FCS + kg] = *(const uint4*)&Alg[ga];
            *(uint4*)&Bh[r * FCS + kg] = *(const uint4*)&Bhg[gb];
            *(uint4*)&Bl[r * FCS + kg] = *(const uint4*)&Blg[gb];
        }
        __syncthreads();

        bf16x8 afh[4], afl[4], bfh[4], bfl[4];
        #pragma unroll
        for (int mt = 0; mt < 4; ++mt) {
            int off = (wr + mt * 16 + m16) * FCS + kb;
            afh[mt] = *(const bf16x8*)&Ah[off];
            afl[mt] = *(const bf16x8*)&Al[off];
        }
        #pragma unroll
        for (int nt = 0; nt < 4; ++nt) {
            int off = (wc + nt * 16 + m16) * FCS + kb;
            bfh[nt] = *(const bf16x8*)&Bh[off];
            bfl[nt] = *(const bf16x8*)&Bl[off];
        }
        #pragma unroll
        for (int mt = 0; mt < 4; ++mt)
            #pragma unroll
            for (int nt = 0; nt < 4; ++nt) {
                acc[mt][nt] = __builtin_amdgcn_mfma_f32_16x16x32_bf16(afh[mt], bfh[nt], acc[mt][nt], 0, 0, 0);
                acc[mt][nt] = __builtin_amdgcn_mfma_f32_16x16x32_bf16(afl[mt], bfh[nt], acc[mt][nt], 0, 0, 0);
                acc[mt][nt] = __builtin_amdgcn_mfma_f32_16x16x32_bf16(afh[mt], bfl[nt], acc[mt][nt], 0, 0, 0);
            }
        __syncthreads();
    }

    #pragma unroll
    for (int mt = 0; mt < 4; ++mt)
        #pragma unroll
        for (int nt = 0; nt < 4; ++nt)
            #pragma unroll
            for (int r = 0; r < 4; ++r) {
                int rr = m0 + wr + mt * 16 + (lane >> 4) * 4 + r;
                int cc = n0 + wc + nt * 16 + m16;
                float v = acc[mt][nt][r] + bias[cc];
                v = (v > 0.f) ? v : 0.01f * v;
                if (Cf) {
                    Cf[(size_t)rr * N + cc] = v;
                } else {
                    unsigned int uv = __float_as_uint(v);
                    Chh[(size_t)rr * N + cc] = (unsigned short)(uv >> 16);
                    Chl[(size_t)rr * N + cc] =
                        f2bf_rne(v - __uint_as_float(uv & 0xFFFF0000u));
                }
            }
}

// ---------------------------------------------------------------------------
// Kernel 5: FC3 [1024,1024] @ [20,1024]^T + bias -> d_out [1024,20]
// ---------------------------------------------------------------------------
__global__ __launch_bounds__(256) void k_fc3(
    const float* __restrict__ A, const float* __restrict__ W,
    const float* __restrict__ bias, float* __restrict__ out)
{
    __shared__ float row[1024];
    __shared__ float red[20][8];
    const int m = blockIdx.x;
    const int t = threadIdx.x;
    #pragma unroll
    for (int r = 0; r < 4; ++r) row[r * 256 + t] = A[(size_t)m * 1024 + r * 256 + t];
    __syncthreads();
    if (t < 160) {
        int o = t >> 3, seg = t & 7;
        const float* w = W + (size_t)o * 1024 + seg * 128;
        const float* rr = &row[seg * 128];
        float s = 0.f;
        for (int kk = 0; kk < 128; ++kk) s += rr[kk] * w[kk];
        red[o][seg] = s;
    }
    __syncthreads();
    if (t < 20) {
        float s = bias[t];
        #pragma unroll
        for (int seg = 0; seg < 8; ++seg) s += red[t][seg];
        out[(size_t)m * 20 + t] = s;
    }
}

// ---------------------------------------------------------------------------
extern "C" void kernel_launch(void* const* d_in, const int* in_sizes, int n_in,
                              void* d_out, int out_size, void* d_ws, size_t ws_size,
                              hipStream_t stream) {
    const float* in1    = (const float*)d_in[0];
    const float* in2    = (const float*)d_in[1];
    const float* w_x_q  = (const float*)d_in[2];
    const float* w_x_k  = (const float*)d_in[3];
    const float* w_y_q  = (const float*)d_in[4];
    const float* w_y_k  = (const float*)d_in[5];
    const float* posemb = (const float*)d_in[6];
    const float* conv_w = (const float*)d_in[7];
    const float* conv_b = (const float*)d_in[8];
    const float* bn_g   = (const float*)d_in[9];
    const float* bn_b   = (const float*)d_in[10];
    const float* bn_m   = (const float*)d_in[11];
    const float* bn_v   = (const float*)d_in[12];
    const float* Wih0   = (const float*)d_in[13];
    const float* Whh0   = (const float*)d_in[14];
    const float* bih0   = (const float*)d_in[15];
    const float* bhh0   = (const float*)d_in[16];
    const float* Wih1   = (const float*)d_in[17];
    const float* Whh1   = (const float*)d_in[18];
    const float* bih1   = (const float*)d_in[19];
    const float* bhh1   = (const float*)d_in[20];
    const float* fc1w   = (const float*)d_in[21];
    const float* fc1b   = (const float*)d_in[22];
    const float* fc2w   = (const float*)d_in[23];
    const float* fc2b   = (const float*)d_in[24];
    const float* fc3w   = (const float*)d_in[25];
    const float* fc3b   = (const float*)d_in[26];
    float* out = (float*)d_out;

    float* ws = (float*)d_ws;
    float* pre0            = ws;                               // 8,466,432
    unsigned short* fbh    = (unsigned short*)(ws + 8466432);  // 2,097,152 us
    unsigned short* fbl    = (unsigned short*)(ws + 9515008);
    unsigned short* f1h    = (unsigned short*)(ws + 10563584); // 1,048,576 us
    unsigned short* f1l    = (unsigned short*)(ws + 11087872);
    float* f2              = ws + 11612160;                    // 1,048,576 f
    unsigned short* w1h    = (unsigned short*)(ws + 12660736); // 2,097,152 us
    unsigned short* w1l    = (unsigned short*)(ws + 13709312);
    unsigned short* w2h    = (unsigned short*)(ws + 14757888); // 1,048,576 us
    unsigned short* w2l    = (unsigned short*)(ws + 15282176);
    unsigned short* Wfh    = (unsigned short*)(ws + 15806464); // 30,720 us
    unsigned short* Wfl    = (unsigned short*)(ws + 15821824);

    k_permW<<<120, 256, 0, stream>>>(Wih0, Wfh, Wfl);
    k_cvt<<<2048, 256, 0, stream>>>(fc1w, w1h, w1l, 524288);
    k_cvt<<<1024, 256, 0, stream>>>(fc2w, w2h, w2l, 262144);
    k_attn_conv<<<1024, 256, 0, stream>>>(in1, in2, w_x_q, w_x_k, w_y_q, w_y_k,
                                          posemb, conv_w, conv_b, bn_g, bn_b,
                                          bn_m, bn_v, Wfh, Wfl, pre0);
    k_lstm<<<256, 64, 0, stream>>>(pre0, Whh0, Wih1, Whh1,
                                   bih0, bhh0, bih1, bhh1, fbh, fbl);
    dim3 gfc(8, 8);
    k_fcmm<<<gfc, 256, 0, stream>>>(fbh, fbl, w1h, w1l, fc1b,
                                    nullptr, f1h, f1l, 1024, 2048);
    k_fcmm<<<gfc, 256, 0, stream>>>(f1h, f1l, w2h, w2l, fc2b,
                                    f2, nullptr, nullptr, 1024, 1024);
    k_fc3<<<1024, 256, 0, stream>>>(f2, fc3w, fc3b, out);
}